// Round 8
// baseline (1867.890 us; speedup 1.0000x reference)
//
#include <hip/hip_runtime.h>
#include <cmath>

// (B, L, D, H) = (256, 32, 512, 512)
#define B_   256
#define L_   32
#define H_   512
#define NH5  2560   // 5*H
#define N2   5120   // 2*NH5 : [al | ar] output width
#define SCALE 0.044194173824159216f  // 1/sqrt(H)

typedef short bf16x8 __attribute__((ext_vector_type(8)));
typedef float f32x4  __attribute__((ext_vector_type(4)));

#define HSZ (8192ull*512ull)   // h-limb plane (row-major k)
#define WSZ (5120ull*512ull)   // W-limb plane (n-major k; n>=2560 -> ar cols)

// ---------------- persistent device state (re-initialized every launch) ----
__device__ float g_h [B_*L_*H_];
__device__ float g_c [B_*L_*H_];
__device__ float g_al[(size_t)B_*L_*NH5];
__device__ float g_ar[(size_t)B_*L_*NH5];
__device__ float g_logit[B_*L_];
__device__ int   g_list[B_*L_];
__device__ int   g_count[B_];
__device__ int   g_merged[B_];
__device__ int   g_mpos[B_];
__device__ int   g_off[B_];
__device__ int   g_rows[B_*L_];
__device__ int   g_nrows;
__device__ int   g_mlist[2][B_];
__device__ int   g_cnt[2];
__device__ unsigned short g_hL[3*HSZ];   // 3-limb bf16 of h rows
__device__ unsigned short g_wL[3*WSZ];   // 3-limb bf16 of W_comp (rearranged)

__device__ __forceinline__ float sigm(float x) { return 1.0f / (1.0f + expf(-x)); }

// truncation limb split: f = bf(a) + bf(b) + bf(c) + O(2^-24 f)
__device__ __forceinline__ void limb3(float f, unsigned short& a,
                                      unsigned short& b, unsigned short& c) {
  unsigned u0 = __float_as_uint(f); a = (unsigned short)(u0 >> 16);
  float r1 = f - __uint_as_float(u0 & 0xffff0000u);          // exact
  unsigned u1 = __float_as_uint(r1); b = (unsigned short)(u1 >> 16);
  float r2 = r1 - __uint_as_float(u1 & 0xffff0000u);         // exact
  c = (unsigned short)(__float_as_uint(r2) >> 16);
}

// ---------------- init ------------------------------------------------------
__global__ __launch_bounds__(256) void init_all(const int* __restrict__ length) {
  __shared__ int sw[4];
  const int t = threadIdx.x;
  const int len = length[t];
  int v = len;
#pragma unroll
  for (int off = 1; off < 64; off <<= 1) {
    int o = __shfl_up(v, off, 64);
    if ((t & 63) >= off) v += o;
  }
  if ((t & 63) == 63) sw[t >> 6] = v;
  __syncthreads();
  int base = 0;
  for (int w = 0; w < (t >> 6); w++) base += sw[w];
  const int incl = base + v;
  const int off0 = incl - len;
  g_off[t] = off0;
  if (t == 255) g_nrows = incl;
  g_count[t] = len; g_merged[t] = -2; g_mpos[t] = 0;
  if (t == 0) { g_cnt[0] = 0; g_cnt[1] = 0; }
#pragma unroll
  for (int s = 0; s < L_; s++) g_list[t*L_ + s] = s;
  for (int s = 0; s < len; s++) g_rows[off0 + s] = t*L_ + s;
}

// ---------------- one-time W_comp -> bf16 limbs (rearranged [n][k]) --------
__global__ __launch_bounds__(128) void convert_w(const float* __restrict__ Wc) {
  const int n = blockIdx.x;                  // 0..5119
  const float* src = (n < NH5) ? Wc + (size_t)n * 1024
                               : Wc + (size_t)(n - NH5) * 1024 + 512;
  const int k = threadIdx.x * 4;
  float4 f = *(const float4*)(src + k);
  ushort4 u0, u1, u2;
  limb3(f.x, u0.x, u1.x, u2.x); limb3(f.y, u0.y, u1.y, u2.y);
  limb3(f.z, u0.z, u1.z, u2.z); limb3(f.w, u0.w, u1.w, u2.w);
  const size_t base = (size_t)n * 512 + k;
  *(ushort4*)(g_wL + 0*WSZ + base) = u0;
  *(ushort4*)(g_wL + 1*WSZ + base) = u1;
  *(ushort4*)(g_wL + 2*WSZ + base) = u2;
}

// ---------------- word GEMM (fp32, R7-proven) + h-limb epilogue ------------
__global__ __launch_bounds__(256) void gemm_word(
    const float* __restrict__ Aext,
    const float* __restrict__ Bm,
    const float* __restrict__ bias)
{
  const int NR = g_nrows;
  const int m0 = blockIdx.y * 128;
  if (m0 >= NR) return;
  const int n0 = blockIdx.x * 128;

  const int tid = threadIdx.x;
  const int w = tid >> 6, l = tid & 63;
  const int tx = (w & 1) * 8 + (l & 7);
  const int ty = (w >> 1) * 8 + (l >> 3);

  __shared__ float As[8][128];
  __shared__ float Bs[8][128];

  const int ra = tid >> 1, qa = (tid & 1) * 4;

  int mr = m0 + ra; if (mr >= NR) mr = NR - 1;
  const float* aptr = Aext + (size_t)g_rows[mr] * 512 + qa;
  const float* bptr = Bm + (size_t)(n0 + ra) * 512 + qa;

  float4 av = *(const float4*)(aptr);
  float4 bv = *(const float4*)(bptr);
  float acc[8][8] = {};

  for (int k0 = 0; k0 < 512; k0 += 8) {
    __syncthreads();
    As[qa+0][ra] = av.x; As[qa+1][ra] = av.y; As[qa+2][ra] = av.z; As[qa+3][ra] = av.w;
    Bs[qa+0][ra] = bv.x; Bs[qa+1][ra] = bv.y; Bs[qa+2][ra] = bv.z; Bs[qa+3][ra] = bv.w;
    __syncthreads();
    if (k0 + 8 < 512) {
      av = *(const float4*)(aptr + k0 + 8);
      bv = *(const float4*)(bptr + k0 + 8);
    }
#pragma unroll
    for (int k = 0; k < 8; k++) {
      float af[8], bf[8];
#pragma unroll
      for (int c = 0; c < 2; c++) {
        float4 t = *(const float4*)&As[k][ty*8 + 4*c];
        af[4*c+0]=t.x; af[4*c+1]=t.y; af[4*c+2]=t.z; af[4*c+3]=t.w;
      }
#pragma unroll
      for (int c = 0; c < 2; c++) {
        float4 t = *(const float4*)&Bs[k][tx*8 + 4*c];
        bf[4*c+0]=t.x; bf[4*c+1]=t.y; bf[4*c+2]=t.z; bf[4*c+3]=t.w;
      }
#pragma unroll
      for (int i = 0; i < 8; i++)
#pragma unroll
        for (int j = 0; j < 8; j++)
          acc[i][j] = fmaf(af[i], bf[j], acc[i][j]);
    }
  }

  const int nb = n0 + tx*8;
  float4 bias_lo = *(const float4*)(bias + nb);
  float4 bias_hi = *(const float4*)(bias + nb + 4);
#pragma unroll
  for (int i = 0; i < 8; i++) {
    int mrow = m0 + ty*8 + i;
    if (mrow >= NR) continue;
    int crow = g_rows[mrow];
    float4 v0 = make_float4(acc[i][0]+bias_lo.x, acc[i][1]+bias_lo.y,
                            acc[i][2]+bias_lo.z, acc[i][3]+bias_lo.w);
    float4 v1 = make_float4(acc[i][4]+bias_hi.x, acc[i][5]+bias_hi.y,
                            acc[i][6]+bias_hi.z, acc[i][7]+bias_hi.w);
    if (nb < H_) {
      float* dst = g_h + (size_t)crow*H_ + nb;
      *(float4*)(dst) = v0; *(float4*)(dst + 4) = v1;
      // h-limbs for the MFMA leaf GEMM
      ushort4 a0,a1,a2,b0,b1,b2;
      limb3(v0.x,a0.x,a1.x,a2.x); limb3(v0.y,a0.y,a1.y,a2.y);
      limb3(v0.z,a0.z,a1.z,a2.z); limb3(v0.w,a0.w,a1.w,a2.w);
      limb3(v1.x,b0.x,b1.x,b2.x); limb3(v1.y,b0.y,b1.y,b2.y);
      limb3(v1.z,b0.z,b1.z,b2.z); limb3(v1.w,b0.w,b1.w,b2.w);
      const size_t hb = (size_t)crow*512 + nb;
      *(ushort4*)(g_hL + 0*HSZ + hb) = a0; *(ushort4*)(g_hL + 0*HSZ + hb + 4) = b0;
      *(ushort4*)(g_hL + 1*HSZ + hb) = a1; *(ushort4*)(g_hL + 1*HSZ + hb + 4) = b1;
      *(ushort4*)(g_hL + 2*HSZ + hb) = a2; *(ushort4*)(g_hL + 2*HSZ + hb + 4) = b2;
    } else {
      float* dst = g_c + (size_t)crow*H_ + (nb - H_);
      *(float4*)(dst) = v0; *(float4*)(dst + 4) = v1;
    }
  }
}

// ---------------- leaf GEMM: 3-limb bf16 MFMA (6 products) -----------------
// C[m,n] = sum_k h[m,k] * W[n,k], M=NR rows, N=5120, K=512.
// tile 128x128, BK=32, 4 waves in 2x2 quadrants, 16x16x32 MFMA.
__global__ __launch_bounds__(256) void gemm_leaf(void)
{
  const int NR = g_nrows;
  const int m0 = blockIdx.y * 128;
  if (m0 >= NR) return;
  const int n0 = blockIdx.x * 128;
  const int tid = threadIdx.x;

  __shared__ unsigned short As[3][128][40];  // stride 40 shorts: 16B-aligned rows, 2-way banks
  __shared__ unsigned short Bs[3][128][40];
  __shared__ int s_rows[128];

  if (tid < 128) {
    int mr = m0 + tid; if (mr >= NR) mr = NR - 1;
    s_rows[tid] = g_rows[mr];
  }
  __syncthreads();

  // 768 staging segments (64B each): [0,384)=A (limb,row), [384,768)=B.
  // 3 segments per thread. Base pointers at k=0; advance 4 int4 per chunk.
  const int4* sp[3];
  int4* lw[3];
#pragma unroll
  for (int j = 0; j < 3; j++) {
    int S = tid + j*256;
    if (S < 384) {
      int la = S >> 7, r = S & 127;
      sp[j] = (const int4*)(g_hL + (size_t)la*HSZ + (size_t)s_rows[r]*512);
      lw[j] = (int4*)&As[la][r][0];
    } else {
      S -= 384;
      int la = S >> 7, r = S & 127;
      sp[j] = (const int4*)(g_wL + (size_t)la*WSZ + (size_t)(n0 + r)*512);
      lw[j] = (int4*)&Bs[la][r][0];
    }
  }

  const int lane = tid & 63, w = tid >> 6;
  const int wm = w >> 1, wn = w & 1;
  const int lr = lane & 15, qd = lane >> 4;

  f32x4 acc[4][4];
#pragma unroll
  for (int i = 0; i < 4; i++)
#pragma unroll
    for (int j = 0; j < 4; j++) acc[i][j] = (f32x4){0.f,0.f,0.f,0.f};

  int4 pf[3][4];
#pragma unroll
  for (int j = 0; j < 3; j++)
#pragma unroll
    for (int q = 0; q < 4; q++) pf[j][q] = sp[j][q];

  for (int ch = 0; ch < 16; ++ch) {
    __syncthreads();
#pragma unroll
    for (int j = 0; j < 3; j++)
#pragma unroll
      for (int q = 0; q < 4; q++) lw[j][q] = pf[j][q];
    __syncthreads();
    if (ch < 15) {
#pragma unroll
      for (int j = 0; j < 3; j++)
#pragma unroll
        for (int q = 0; q < 4; q++) pf[j][q] = sp[j][(ch+1)*4 + q];
    }

    bf16x8 af[3][4];
#pragma unroll
    for (int la = 0; la < 3; la++)
#pragma unroll
      for (int mt = 0; mt < 4; mt++)
        af[la][mt] = *(const bf16x8*)&As[la][wm*64 + mt*16 + lr][qd*8];

#pragma unroll
    for (int lb = 0; lb < 3; lb++) {
      bf16x8 bf[4];
#pragma unroll
      for (int nt = 0; nt < 4; nt++)
        bf[nt] = *(const bf16x8*)&Bs[lb][wn*64 + nt*16 + lr][qd*8];
      const int nla = (lb == 0) ? 3 : ((lb == 1) ? 2 : 1);
      for (int la = 0; la < nla; la++)
#pragma unroll
        for (int mt = 0; mt < 4; mt++)
#pragma unroll
          for (int nt = 0; nt < 4; nt++)
            acc[mt][nt] = __builtin_amdgcn_mfma_f32_16x16x32_bf16(
                af[la][mt], bf[nt], acc[mt][nt], 0, 0, 0);
    }
  }

  // epilogue: C/D layout col=lane&15, row=quad*4+reg  [m89-verified]
#pragma unroll
  for (int mt = 0; mt < 4; mt++)
#pragma unroll
    for (int nt = 0; nt < 4; nt++) {
      const int n = n0 + wn*64 + nt*16 + lr;
      float* dst = (n < NH5) ? g_al + n : g_ar + (n - NH5);
#pragma unroll
      for (int r = 0; r < 4; r++) {
        const int ml = wm*64 + mt*16 + qd*4 + r;
        if (m0 + ml >= NR) continue;
        dst[(size_t)s_rows[ml] * NH5] = acc[mt][nt][r];
      }
    }
}

// ---------------- iteration-0 logits ---------------------------------------
__global__ __launch_bounds__(256) void iter0_logits(const int* __restrict__ length,
                                                    const float* __restrict__ bc,
                                                    const float* __restrict__ qv) {
  __shared__ float sred[4];
  const int p = blockIdx.x, b = blockIdx.y;
  if (p >= length[b] - 1) return;
  const float* al = g_al + (size_t)(b*L_ + p)*NH5;
  const float* ar = g_ar + (size_t)(b*L_ + p + 1)*NH5;
  const float* cl = g_c  + (size_t)(b*L_ + p)*H_;
  const float* cr = g_c  + (size_t)(b*L_ + p + 1)*H_;
  float part = 0.f;
#pragma unroll
  for (int jj = 0; jj < H_/256; jj++) {
    int j = threadIdx.x + jj*256;
    float vi  = al[j]       + ar[j]       + bc[j];
    float vfl = al[H_+j]    + ar[H_+j]    + bc[H_+j];
    float vfr = al[2*H_+j]  + ar[2*H_+j]  + bc[2*H_+j];
    float vu  = al[3*H_+j]  + ar[3*H_+j]  + bc[3*H_+j];
    float vo  = al[4*H_+j]  + ar[4*H_+j]  + bc[4*H_+j];
    float c = cl[j]*sigm(vfl+1.f) + cr[j]*sigm(vfr+1.f) + tanhf(vu)*sigm(vi);
    float h = sigm(vo)*tanhf(c);
    part = fmaf(qv[j], h, part);
  }
#pragma unroll
  for (int off = 32; off; off >>= 1) part += __shfl_down(part, off, 64);
  if ((threadIdx.x & 63) == 0) sred[threadIdx.x >> 6] = part;
  __syncthreads();
  if (threadIdx.x == 0)
    g_logit[b*L_ + p] = (sred[0]+sred[1]+sred[2]+sred[3]) * SCALE;
}

// ---------------- per-iteration select + merge (R7-proven) -----------------
__global__ __launch_bounds__(256) void select_merge(int iter,
    const int* __restrict__ length,
    const float* __restrict__ bc,
    const float* __restrict__ qv,
    float* __restrict__ out)
{
  __shared__ float sred[4];
  __shared__ int s_sel[3];
  const int b = blockIdx.x, tid = threadIdx.x;
  if (b == 0 && tid == 0) g_cnt[(iter & 1) ^ 1] = 0;

  const int m     = g_count[b];
  const int pslot = g_merged[b];
  const int ppos  = g_mpos[b];
  int* list = g_list + b*L_;

  if (iter > 0 && pslot >= 0) {
    const int half = tid >> 7, lt = tid & 127;
    int sl = -1, sr = -1;
    if (half == 0) { if (ppos > 0)     { sl = list[ppos-1]; sr = list[ppos];   } }
    else           { if (ppos < m - 1) { sl = list[ppos];   sr = list[ppos+1]; } }
    float part = 0.f;
    if (sl >= 0) {
      const float* al = g_al + (size_t)(b*L_+sl)*NH5;
      const float* ar = g_ar + (size_t)(b*L_+sr)*NH5;
      const float* cl = g_c  + (size_t)(b*L_+sl)*H_;
      const float* cr = g_c  + (size_t)(b*L_+sr)*H_;
      const int j = lt * 4;
      float4 ai  = *(const float4*)(al + j)        , bi  = *(const float4*)(ar + j);
      float4 afl = *(const float4*)(al + H_   + j) , bfl = *(const float4*)(ar + H_   + j);
      float4 afr = *(const float4*)(al + 2*H_ + j) , bfr = *(const float4*)(ar + 2*H_ + j);
      float4 au  = *(const float4*)(al + 3*H_ + j) , bu  = *(const float4*)(ar + 3*H_ + j);
      float4 ao  = *(const float4*)(al + 4*H_ + j) , bo  = *(const float4*)(ar + 4*H_ + j);
      float4 c4l = *(const float4*)(cl + j)        , c4r = *(const float4*)(cr + j);
      float4 q4  = *(const float4*)(qv + j);
      const float* bc0 = bc + j;
      float c, h;
      c = c4l.x*sigm(afl.x+bfl.x+bc0[H_]+1.f)   + c4r.x*sigm(afr.x+bfr.x+bc0[2*H_]+1.f)
        + tanhf(au.x+bu.x+bc0[3*H_])*sigm(ai.x+bi.x+bc0[0]);
      h = sigm(ao.x+bo.x+bc0[4*H_])*tanhf(c);   part = fmaf(q4.x, h, part);
      c = c4l.y*sigm(afl.y+bfl.y+bc0[H_+1]+1.f) + c4r.y*sigm(afr.y+bfr.y+bc0[2*H_+1]+1.f)
        + tanhf(au.y+bu.y+bc0[3*H_+1])*sigm(ai.y+bi.y+bc0[1]);
      h = sigm(ao.y+bo.y+bc0[4*H_+1])*tanhf(c); part = fmaf(q4.y, h, part);
      c = c4l.z*sigm(afl.z+bfl.z+bc0[H_+2]+1.f) + c4r.z*sigm(afr.z+bfr.z+bc0[2*H_+2]+1.f)
        + tanhf(au.z+bu.z+bc0[3*H_+2])*sigm(ai.z+bi.z+bc0[2]);
      h = sigm(ao.z+bo.z+bc0[4*H_+2])*tanhf(c); part = fmaf(q4.z, h, part);
      c = c4l.w*sigm(afl.w+bfl.w+bc0[H_+3]+1.f) + c4r.w*sigm(afr.w+bfr.w+bc0[2*H_+3]+1.f)
        + tanhf(au.w+bu.w+bc0[3*H_+3])*sigm(ai.w+bi.w+bc0[3]);
      h = sigm(ao.w+bo.w+bc0[4*H_+3])*tanhf(c); part = fmaf(q4.w, h, part);
    }
#pragma unroll
    for (int off = 32; off; off >>= 1) part += __shfl_down(part, off, 64);
    if ((tid & 63) == 0) sred[tid >> 6] = part;
    __syncthreads();
    if (tid == 0   && ppos > 0)     g_logit[b*L_ + list[ppos-1]] = (sred[0]+sred[1])*SCALE;
    if (tid == 128 && ppos < m - 1) g_logit[b*L_ + list[ppos]]   = (sred[2]+sred[3])*SCALE;
  }

  const bool active = iter < (length[b] - 1);
  if (active) {
    __syncthreads();

    if (tid < 64) {
      float lg = -1e30f; int idx = tid;
      if (tid < m - 1) lg = g_logit[b*L_ + list[tid]];
#pragma unroll
      for (int off = 32; off; off >>= 1) {
        float olg = __shfl_down(lg, off, 64);
        int   oid = __shfl_down(idx, off, 64);
        if (olg > lg || (olg == lg && oid < idx)) { lg = olg; idx = oid; }
      }
      if (tid == 0) { s_sel[0] = idx; s_sel[1] = list[idx]; s_sel[2] = list[idx+1]; }
    }
    __syncthreads();
    const int pos = s_sel[0], sl = s_sel[1], sr = s_sel[2];

    if (tid < 128) {
      const float* al = g_al + (size_t)(b*L_+sl)*NH5;
      const float* ar = g_ar + (size_t)(b*L_+sr)*NH5;
      float*       cl = g_c  + (size_t)(b*L_+sl)*H_;
      const float* cr = g_c  + (size_t)(b*L_+sr)*H_;
      float*       hl = g_h  + (size_t)(b*L_+sl)*H_;
      const int j = tid * 4;
      float4 ai  = *(const float4*)(al + j)        , bi  = *(const float4*)(ar + j);
      float4 afl = *(const float4*)(al + H_   + j) , bfl = *(const float4*)(ar + H_   + j);
      float4 afr = *(const float4*)(al + 2*H_ + j) , bfr = *(const float4*)(ar + 2*H_ + j);
      float4 au  = *(const float4*)(al + 3*H_ + j) , bu  = *(const float4*)(ar + 3*H_ + j);
      float4 ao  = *(const float4*)(al + 4*H_ + j) , bo  = *(const float4*)(ar + 4*H_ + j);
      float4 c4l = *(const float4*)(cl + j)        , c4r = *(const float4*)(cr + j);
      const float* bc0 = bc + j;
      float4 cn, hn;
      cn.x = c4l.x*sigm(afl.x+bfl.x+bc0[H_]+1.f)   + c4r.x*sigm(afr.x+bfr.x+bc0[2*H_]+1.f)
           + tanhf(au.x+bu.x+bc0[3*H_])*sigm(ai.x+bi.x+bc0[0]);
      hn.x = sigm(ao.x+bo.x+bc0[4*H_])*tanhf(cn.x);
      cn.y = c4l.y*sigm(afl.y+bfl.y+bc0[H_+1]+1.f) + c4r.y*sigm(afr.y+bfr.y+bc0[2*H_+1]+1.f)
           + tanhf(au.y+bu.y+bc0[3*H_+1])*sigm(ai.y+bi.y+bc0[1]);
      hn.y = sigm(ao.y+bo.y+bc0[4*H_+1])*tanhf(cn.y);
      cn.z = c4l.z*sigm(afl.z+bfl.z+bc0[H_+2]+1.f) + c4r.z*sigm(afr.z+bfr.z+bc0[2*H_+2]+1.f)
           + tanhf(au.z+bu.z+bc0[3*H_+2])*sigm(ai.z+bi.z+bc0[2]);
      hn.z = sigm(ao.z+bo.z+bc0[4*H_+2])*tanhf(cn.z);
      cn.w = c4l.w*sigm(afl.w+bfl.w+bc0[H_+3]+1.f) + c4r.w*sigm(afr.w+bfr.w+bc0[2*H_+3]+1.f)
           + tanhf(au.w+bu.w+bc0[3*H_+3])*sigm(ai.w+bi.w+bc0[3]);
      hn.w = sigm(ao.w+bo.w+bc0[4*H_+3])*tanhf(cn.w);
      *(float4*)(cl + j) = cn;
      *(float4*)(hl + j) = hn;
    }
    __syncthreads();
    if (tid == 0) {
      for (int n = pos+1; n < m-1; n++) list[n] = list[n+1];
      g_count[b]  = m - 1;
      g_merged[b] = sl;
      g_mpos[b]   = pos;
      int k = atomicAdd(&g_cnt[iter & 1], 1);
      g_mlist[iter & 1][k] = b;
    }
  } else {
    if (tid == 0) g_merged[b] = -1;
  }

  if (iter == L_-2) {
    __syncthreads();
    for (int j = tid; j < H_; j += 256)
      out[(size_t)b*H_ + j] = g_h[(size_t)(b*L_)*H_ + j];
  }
}

// ---------------- per-iteration a_l/a_r GEMM (R3-proven) -------------------
__global__ __launch_bounds__(256) void gemm_iter(int par, const float* __restrict__ Wc)
{
  const int nact = g_cnt[par];
  const int m0 = blockIdx.y * 32;
  if (m0 >= nact) return;
  const int n0 = blockIdx.x * 64;
  const int tid = threadIdx.x;

  __shared__ float As[32][32];
  __shared__ float Bs[32][64];

  const int ra = tid >> 3, qa = (tid & 7) * 4;
  int mr = m0 + ra; if (mr >= nact) mr = nact - 1;
  const int bbA = g_mlist[par][mr];
  const float* aptr = g_h + (size_t)(bbA*L_ + g_merged[bbA]) * 512 + qa;

  const int rb = tid >> 2, qb = (tid & 3) * 8;
  const int nr = n0 + rb;
  const float* bptr = (nr < NH5) ? Wc + (size_t)nr * 1024 + qb
                                 : Wc + (size_t)(nr - NH5) * 1024 + 512 + qb;

  const int tx = tid & 15, ty = tid >> 4;

  float4 av  = *(const float4*)(aptr);
  float4 bv0 = *(const float4*)(bptr);
  float4 bv1 = *(const float4*)(bptr + 4);
  float acc[2][4] = {};

  for (int k0 = 0; k0 < 512; k0 += 32) {
    __syncthreads();
    As[qa+0][ra] = av.x;  As[qa+1][ra] = av.y;  As[qa+2][ra] = av.z;  As[qa+3][ra] = av.w;
    Bs[qb+0][rb] = bv0.x; Bs[qb+1][rb] = bv0.y; Bs[qb+2][rb] = bv0.z; Bs[qb+3][rb] = bv0.w;
    Bs[qb+4][rb] = bv1.x; Bs[qb+5][rb] = bv1.y; Bs[qb+6][rb] = bv1.z; Bs[qb+7][rb] = bv1.w;
    __syncthreads();
    if (k0 + 32 < 512) {
      av  = *(const float4*)(aptr + k0 + 32);
      bv0 = *(const float4*)(bptr + k0 + 32);
      bv1 = *(const float4*)(bptr + k0 + 36);
    }
#pragma unroll
    for (int k = 0; k < 32; k++) {
      float2 a2 = *(const float2*)&As[k][ty*2];
      float4 b4 = *(const float4*)&Bs[k][tx*4];
      acc[0][0] = fmaf(a2.x, b4.x, acc[0][0]);
      acc[0][1] = fmaf(a2.x, b4.y, acc[0][1]);
      acc[0][2] = fmaf(a2.x, b4.z, acc[0][2]);
      acc[0][3] = fmaf(a2.x, b4.w, acc[0][3]);
      acc[1][0] = fmaf(a2.y, b4.x, acc[1][0]);
      acc[1][1] = fmaf(a2.y, b4.y, acc[1][1]);
      acc[1][2] = fmaf(a2.y, b4.z, acc[1][2]);
      acc[1][3] = fmaf(a2.y, b4.w, acc[1][3]);
    }
  }

#pragma unroll
  for (int i = 0; i < 2; i++) {
    int mrow = m0 + ty*2 + i;
    if (mrow >= nact) continue;
    int bb = g_mlist[par][mrow];
    size_t base = (size_t)(bb*L_ + g_merged[bb]) * NH5;
    int n = n0 + tx*4;
    float4 v = make_float4(acc[i][0], acc[i][1], acc[i][2], acc[i][3]);
    if (n < NH5) *(float4*)(g_al + base + n)         = v;
    else         *(float4*)(g_ar + base + (n - NH5)) = v;
  }
}

// ---------------------------------------------------------------------------
extern "C" void kernel_launch(void* const* d_in, const int* in_sizes, int n_in,
                              void* d_out, int out_size, void* d_ws, size_t ws_size,
                              hipStream_t stream)
{
  (void)in_sizes; (void)n_in; (void)out_size; (void)d_ws; (void)ws_size;
  const float* x      = (const float*)d_in[0];
  const int*   length = (const int*)  d_in[1];
  const float* W_word = (const float*)d_in[2];
  const float* b_word = (const float*)d_in[3];
  const float* W_comp = (const float*)d_in[4];
  const float* b_comp = (const float*)d_in[5];
  const float* q      = (const float*)d_in[6];
  float* out = (float*)d_out;

  init_all<<<1, 256, 0, stream>>>(length);
  convert_w<<<N2, 128, 0, stream>>>(W_comp);

  gemm_word<<<dim3(1024/128, 64), 256, 0, stream>>>(x, W_word, b_word);
  gemm_leaf<<<dim3(N2/128, 64), 256, 0, stream>>>();

  iter0_logits<<<dim3(L_-1, B_), 256, 0, stream>>>(length, b_comp, q);

  for (int i = 0; i < L_-1; i++) {
    select_merge<<<B_, 256, 0, stream>>>(i, length, b_comp, q, out);
    if (i < L_-2)
      gemm_iter<<<dim3(N2/64, 8), 256, 0, stream>>>(i & 1, W_comp);
  }
}